// Round 14
// baseline (1269.841 us; speedup 1.0000x reference)
//
#include <hip/hip_runtime.h>
#include <hip/hip_bf16.h>
#include <hip/hip_cooperative_groups.h>
#include <math.h>

namespace cg = cooperative_groups;

#define N_NODES 50000
#define N_EDGES 800000
#define IN_C 128
#define HID_C 96
#define OUT_C 64
#define BN_EPS 1e-5f

// ELL edge storage: 64 slots/row. deg ~ Poisson(16); P(deg>64) ~ 1e-17.
#define ELL_SHIFT 6
#define ELL_CAP   64

// Mega-kernel geometry: 1024 blocks x 256 threads = 4 blocks/CU (16 waves/CU).
// LDS-free gemm keeps static LDS ~9 KB so 4 blocks/CU are co-resident;
// __launch_bounds__(256,4) caps VGPR at 128 to guarantee it.
#define GRID_BLKS 1024
#define BLK 256
#define GEMM_BLKS 384   // phase-1 split: blocks [0,384) gemm1, [384,1024) fill

typedef __attribute__((ext_vector_type(8))) short short8;   // 8 bf16 = 4 VGPRs
typedef __attribute__((ext_vector_type(4))) float f32x4;    // MFMA acc

union U16x8 { ushort4 u[2]; short8 s; };

static __device__ __forceinline__ unsigned short f2b(float f) {
    __hip_bfloat16 b = __float2bfloat16(f);   // RNE
    return *reinterpret_cast<unsigned short*>(&b);
}
static __device__ __forceinline__ float b2f(unsigned short u) {
    return __uint_as_float((unsigned)u << 16);  // exact
}

struct GArgs {
    const float* x; const float* ew; const int* row; const int* col;
    const float* W1; const float* W2; const float* W3; const float* b3;
    const float* g1; const float* be1; const float* g2; const float* be2;
    float* out;
    unsigned short* A; unsigned short* Bt;
    unsigned short* Wt1; unsigned short* Wt2; unsigned short* Wt3;
    int2* pairs; int* cnt; float* stats1; float* stats2;
};

// ---------------------------------------------------------------------------
// Device phase: LDS-free MFMA GEMM. h[N,J] = x[N,K] @ W[K,J].
// A-fragment read per lane straight from global (the 4 same-m16 lanes of a
// wave's quads cover a contiguous 64B run of the row — every byte used);
// B-fragment from global Wt[J][K] (18-24 KB, L1-resident after tile 0).
// mfma_f32_16x16x32_bf16 layouts (HW-verified, carried from R10-R13):
//   A: lane holds X[m=lane&15][k=(lane>>4)*8+j]
//   B: lane holds W[k=(lane>>4)*8+j][n=lane&15]  (= row n of W^T)
//   D: lane,reg r -> row m=(lane>>4)*4+r, col n=lane&15
// APPLY: previous layer's BN finalize+apply+ReLU fused into the A read
// (conv bias cancels inside BN — mean absorbs it).
// ---------------------------------------------------------------------------
template <int K, int J, bool APPLY, bool XBF16>
static __device__ void gemm_phase(const void* __restrict__ xin,
                                  const unsigned short* __restrict__ Wt,
                                  const float* __restrict__ stats,
                                  const float* __restrict__ gamma,
                                  const float* __restrict__ beta,
                                  unsigned short* __restrict__ h,
                                  int b0, int nbG, float* scshS) {
    int tid = threadIdx.x;
    if (APPLY) {
        if (tid < K) {
            const float invN = 1.f / N_NODES;
            float mean = stats[tid] * invN;
            float var = stats[K + tid] * invN - mean * mean;
            float sc = gamma[tid] * rsqrtf(var + BN_EPS);
            scshS[tid] = sc;
            scshS[K + tid] = beta[tid] - mean * sc;
        }
        __syncthreads();
    }
    constexpr int NT = J / 16;
    const int NTILES = (N_NODES + 63) / 64;
    int lane = tid & 63, w = tid >> 6, m16 = lane & 15, quad = lane >> 4;

    for (int tile = b0; tile < NTILES; tile += nbG) {
        int tileBase = tile * 64;
        int arow = min(tileBase + w * 16 + m16, N_NODES - 1);
        f32x4 acc[NT];
#pragma unroll
        for (int nt = 0; nt < NT; ++nt) acc[nt] = (f32x4){0.f, 0.f, 0.f, 0.f};

#pragma unroll
        for (int k0 = 0; k0 < K; k0 += 32) {
            U16x8 cv;
            if (XBF16) {
                const unsigned short* src =
                    (const unsigned short*)xin + (size_t)arow * K + k0 + quad * 8;
                cv.u[0] = *(const ushort4*)(src);
                cv.u[1] = *(const ushort4*)(src + 4);
                if (APPLY) {
#pragma unroll
                    for (int j = 0; j < 8; ++j) {
                        int kk = k0 + quad * 8 + j;
                        float v = fmaxf(
                            b2f(((unsigned short*)&cv)[j]) * scshS[kk] + scshS[K + kk],
                            0.f);
                        ((unsigned short*)&cv)[j] = f2b(v);
                    }
                }
            } else {
                const float* src = (const float*)xin + (size_t)arow * K + k0 + quad * 8;
                float4 v0 = *(const float4*)(src);
                float4 v1 = *(const float4*)(src + 4);
                cv.u[0] = make_ushort4(f2b(v0.x), f2b(v0.y), f2b(v0.z), f2b(v0.w));
                cv.u[1] = make_ushort4(f2b(v1.x), f2b(v1.y), f2b(v1.z), f2b(v1.w));
            }
            short8 af = cv.s;
#pragma unroll
            for (int nt = 0; nt < NT; ++nt) {
                short8 bf = *(const short8*)(Wt + (size_t)(nt * 16 + m16) * K +
                                             k0 + quad * 8);
                acc[nt] = __builtin_amdgcn_mfma_f32_16x16x32_bf16(af, bf, acc[nt],
                                                                  0, 0, 0);
            }
        }
#pragma unroll
        for (int nt = 0; nt < NT; ++nt) {
#pragma unroll
            for (int r = 0; r < 4; ++r) {
                int node = tileBase + w * 16 + quad * 4 + r;
                if (node < N_NODES)
                    h[(size_t)node * J + nt * 16 + m16] = f2b(acc[nt][r]);
            }
        }
    }
}

// ---------------------------------------------------------------------------
// Device phase: ELL fill — one-pass permutation scatter (ledger: R7/R9 win;
// R8 block-bins 10x worse; R11 bucket-cursors 4x worse; 50K atomic addresses
// avoid serialization). Runs on blocks [GEMM_BLKS, GRID) concurrently with
// gemm1 (independent work, MFMA-bound vs writeback-bound — m114 overlap).
// ---------------------------------------------------------------------------
static __device__ void fill_phase(const int* __restrict__ row,
                                  const int* __restrict__ col,
                                  const float* __restrict__ ew,
                                  int* __restrict__ cnt,
                                  int2* __restrict__ pairs, int fb, int nfb) {
    for (int e = fb * BLK + (int)threadIdx.x; e < N_EDGES; e += nfb * BLK) {
        int r = row[e];
        int slot = atomicAdd(&cnt[r], 1);
        if (slot < ELL_CAP)
            pairs[((size_t)r << ELL_SHIFT) + slot] =
                make_int2(col[e], __float_as_int(ew[e]));
    }
}

// ---------------------------------------------------------------------------
// Device phase: ELL aggregation (free-running grid-stride, no block barrier
// — R6 lesson; 4-way edge unroll for MLP). Non-LSM writes bf16 B table;
// LSM fuses +b3 and log_softmax (16-lane shuffle groups; stride is a
// multiple of 64 and N*G a multiple of 16, so groups stay wave-intact).
// ---------------------------------------------------------------------------
template <int D, bool LSM>
static __device__ void agg_phase(const unsigned short* __restrict__ h,
                                 const int* __restrict__ cnt,
                                 const int2* __restrict__ pairs,
                                 unsigned short* __restrict__ outb,
                                 float* __restrict__ outf,
                                 const float* __restrict__ b3) {
    constexpr int G = D / 4;
    for (int t = blockIdx.x * BLK + (int)threadIdx.x; t < N_NODES * G;
         t += gridDim.x * BLK) {
        int n = t / G, g = t % G;
        int end = min(cnt[n], ELL_CAP);
        const int2* ep = pairs + ((size_t)n << ELL_SHIFT);
        float4 acc = make_float4(0.f, 0.f, 0.f, 0.f);
        float4 acc2 = make_float4(0.f, 0.f, 0.f, 0.f);
        int i = 0;
        for (; i + 3 < end; i += 4) {
            int2 p0 = ep[i], p1 = ep[i + 1], p2 = ep[i + 2], p3 = ep[i + 3];
            ushort4 u0 = *(const ushort4*)(h + (size_t)p0.x * D + g * 4);
            ushort4 u1 = *(const ushort4*)(h + (size_t)p1.x * D + g * 4);
            ushort4 u2 = *(const ushort4*)(h + (size_t)p2.x * D + g * 4);
            ushort4 u3 = *(const ushort4*)(h + (size_t)p3.x * D + g * 4);
            float w0 = __int_as_float(p0.y), w1 = __int_as_float(p1.y);
            float w2 = __int_as_float(p2.y), w3 = __int_as_float(p3.y);
            acc.x += w0 * b2f(u0.x); acc.y += w0 * b2f(u0.y);
            acc.z += w0 * b2f(u0.z); acc.w += w0 * b2f(u0.w);
            acc2.x += w1 * b2f(u1.x); acc2.y += w1 * b2f(u1.y);
            acc2.z += w1 * b2f(u1.z); acc2.w += w1 * b2f(u1.w);
            acc.x += w2 * b2f(u2.x); acc.y += w2 * b2f(u2.y);
            acc.z += w2 * b2f(u2.z); acc.w += w2 * b2f(u2.w);
            acc2.x += w3 * b2f(u3.x); acc2.y += w3 * b2f(u3.y);
            acc2.z += w3 * b2f(u3.z); acc2.w += w3 * b2f(u3.w);
        }
        for (; i < end; ++i) {
            int2 p = ep[i];
            float w = __int_as_float(p.y);
            ushort4 u = *(const ushort4*)(h + (size_t)p.x * D + g * 4);
            acc.x += w * b2f(u.x); acc.y += w * b2f(u.y);
            acc.z += w * b2f(u.z); acc.w += w * b2f(u.w);
        }
        acc.x += acc2.x; acc.y += acc2.y; acc.z += acc2.z; acc.w += acc2.w;

        if (LSM) {
            float4 bv = *(const float4*)(b3 + g * 4);
            float4 v = make_float4(acc.x + bv.x, acc.y + bv.y,
                                   acc.z + bv.z, acc.w + bv.w);
            float m = fmaxf(fmaxf(v.x, v.y), fmaxf(v.z, v.w));
#pragma unroll
            for (int mask = 1; mask < 16; mask <<= 1)
                m = fmaxf(m, __shfl_xor(m, mask, 16));
            float s = expf(v.x - m) + expf(v.y - m) + expf(v.z - m) + expf(v.w - m);
#pragma unroll
            for (int mask = 1; mask < 16; mask <<= 1)
                s += __shfl_xor(s, mask, 16);
            float l = m + logf(s);
            *(float4*)(outf + (size_t)n * D + g * 4) =
                make_float4(v.x - l, v.y - l, v.z - l, v.w - l);
        } else {
            ushort4 o = make_ushort4(f2b(acc.x), f2b(acc.y), f2b(acc.z), f2b(acc.w));
            *(ushort4*)(outb + (size_t)n * D + g * 4) = o;
        }
    }
}

// ---------------------------------------------------------------------------
// Device phase: BN stats from bf16 B table. 240 active threads = 10 rows x
// 24 groups, register accumulation, LDS transpose-reduce, 192 atomics/block.
// ---------------------------------------------------------------------------
static __device__ void bn_stats_phase(const unsigned short* __restrict__ a,
                                      float* __restrict__ sums, float* sh) {
    constexpr int G = HID_C / 4;   // 24
    constexpr int ROWS = 10;       // 240 active threads
    int tid = threadIdx.x;
    if (tid < G * ROWS) {
        int g = tid % G, r0 = tid / G;
        float4 s4 = make_float4(0.f, 0.f, 0.f, 0.f);
        float4 q4 = make_float4(0.f, 0.f, 0.f, 0.f);
        for (int r = blockIdx.x * ROWS + r0; r < N_NODES; r += gridDim.x * ROWS) {
            ushort4 u = *(const ushort4*)(a + (size_t)r * HID_C + g * 4);
            float vx = b2f(u.x), vy = b2f(u.y), vz = b2f(u.z), vw = b2f(u.w);
            s4.x += vx; s4.y += vy; s4.z += vz; s4.w += vw;
            q4.x += vx * vx; q4.y += vy * vy; q4.z += vz * vz; q4.w += vw * vw;
        }
        *(float4*)&sh[r0 * HID_C + g * 4] = s4;
        *(float4*)&sh[ROWS * HID_C + r0 * HID_C + g * 4] = q4;
    }
    __syncthreads();
    if (tid < HID_C) {
        float s0 = 0.f, s1 = 0.f;
#pragma unroll
        for (int k = 0; k < ROWS; ++k) {
            s0 += sh[k * HID_C + tid];
            s1 += sh[ROWS * HID_C + k * HID_C + tid];
        }
        atomicAdd(&sums[tid], s0);
        atomicAdd(&sums[HID_C + tid], s1);
    }
}

// ---------------------------------------------------------------------------
// THE MEGA-KERNEL: all 9 phases, 8 grid syncs (replacing ~8.5us dispatch
// boundaries with ~1.5us barriers; R12->R13 measured ~8.6us/boundary).
// ---------------------------------------------------------------------------
__global__ __launch_bounds__(BLK, 4) void gcn_mega(GArgs a) {
    cg::grid_group grid = cg::this_grid();
    const int nb = gridDim.x;
    const int b = blockIdx.x, tid = threadIdx.x;
    const int gt = b * BLK + tid;
    const int nt_tot = nb * BLK;

    __shared__ __align__(16) float smemF[2 * 10 * HID_C];  // bn_stats (7.7 KB)
    __shared__ float scshS[2 * IN_C];                      // BN scale/shift

    // ---- phase 0: prep (weight transpose to bf16, zero cnt + stats) ----
    {
        const int n1 = IN_C * HID_C, n2 = HID_C * HID_C, n3 = HID_C * OUT_C;
        for (int i = gt; i < N_NODES; i += nt_tot) {
            if (i < n1) {
                int j = i / IN_C, k = i % IN_C;
                a.Wt1[i] = f2b(a.W1[k * HID_C + j]);
            } else if (i < n1 + n2) {
                int t2 = i - n1, j = t2 / HID_C, k = t2 % HID_C;
                a.Wt2[t2] = f2b(a.W2[k * HID_C + j]);
            } else if (i < n1 + n2 + n3) {
                int t2 = i - n1 - n2, j = t2 / HID_C, k = t2 % HID_C;
                a.Wt3[t2] = f2b(a.W3[k * OUT_C + j]);
            }
            a.cnt[i] = 0;
            if (i < 4 * HID_C) a.stats1[i] = 0.f;   // stats1|stats2 contiguous
        }
    }
    grid.sync();

    // ---- phase 1: gemm1 (blocks [0,GEMM_BLKS)) || fill (the rest) ----
    if (b < GEMM_BLKS)
        gemm_phase<IN_C, HID_C, false, false>(a.x, a.Wt1, nullptr, nullptr,
                                              nullptr, a.A, b, GEMM_BLKS, scshS);
    else
        fill_phase(a.row, a.col, a.ew, a.cnt, a.pairs, b - GEMM_BLKS,
                   nb - GEMM_BLKS);
    grid.sync();

    // ---- phase 2: agg96 A -> Bt ----
    agg_phase<HID_C, false>(a.A, a.cnt, a.pairs, a.Bt, nullptr, nullptr);
    grid.sync();

    // ---- phase 3: BN1 stats ----
    bn_stats_phase(a.Bt, a.stats1, smemF);
    grid.sync();

    // ---- phase 4: gemm2 (BN1 finalize+apply+ReLU fused) Bt -> A ----
    gemm_phase<HID_C, HID_C, true, true>(a.Bt, a.Wt2, a.stats1, a.g1, a.be1,
                                         a.A, b, nb, scshS);
    grid.sync();

    // ---- phase 5: agg96 A -> Bt ----
    agg_phase<HID_C, false>(a.A, a.cnt, a.pairs, a.Bt, nullptr, nullptr);
    grid.sync();

    // ---- phase 6: BN2 stats ----
    bn_stats_phase(a.Bt, a.stats2, smemF);
    grid.sync();

    // ---- phase 7: gemm3 (BN2 fused) Bt -> A ----
    gemm_phase<HID_C, OUT_C, true, true>(a.Bt, a.Wt3, a.stats2, a.g2, a.be2,
                                         a.A, b, nb, scshS);
    grid.sync();

    // ---- phase 8: agg64 + b3 + log_softmax -> out ----
    agg_phase<OUT_C, true>(a.A, a.cnt, a.pairs, nullptr, a.out, a.b3);
}

// ===========================================================================
// FALLBACK PATH (R13, 274.6us): used if the cooperative launch is rejected
// (e.g. graph-capture incompatibility or co-residency failure).
// ===========================================================================
__global__ void prep_all(const float* __restrict__ W1, const float* __restrict__ W2,
                         const float* __restrict__ W3,
                         unsigned short* __restrict__ Wt1,
                         unsigned short* __restrict__ Wt2,
                         unsigned short* __restrict__ Wt3,
                         int* __restrict__ cnt, float* __restrict__ stats) {
    int i = blockIdx.x * blockDim.x + threadIdx.x;
    const int n1 = IN_C * HID_C, n2 = HID_C * HID_C, n3 = HID_C * OUT_C;
    if (i < n1) {
        int j = i / IN_C, k = i % IN_C;
        Wt1[i] = f2b(W1[k * HID_C + j]);
    } else if (i < n1 + n2) {
        int t = i - n1, j = t / HID_C, k = t % HID_C;
        Wt2[t] = f2b(W2[k * HID_C + j]);
    } else if (i < n1 + n2 + n3) {
        int t = i - n1 - n2, j = t / HID_C, k = t % HID_C;
        Wt3[t] = f2b(W3[k * OUT_C + j]);
    }
    if (i < N_NODES) cnt[i] = 0;
    if (i < 4 * HID_C) stats[i] = 0.f;
}

__global__ void fill_ell(const int* __restrict__ row, const int* __restrict__ col,
                         const float* __restrict__ ew, int* __restrict__ cnt,
                         int2* __restrict__ pairs) {
    int e = blockIdx.x * blockDim.x + threadIdx.x;
    if (e >= N_EDGES) return;
    int r = row[e];
    int slot = atomicAdd(&cnt[r], 1);
    if (slot < ELL_CAP)
        pairs[((size_t)r << ELL_SHIFT) + slot] =
            make_int2(col[e], __float_as_int(ew[e]));
}

template <int K, int J, bool APPLY, bool XBF16>
__global__ __launch_bounds__(256) void gemm_k(const void* xin,
                                              const unsigned short* Wt,
                                              const float* stats,
                                              const float* gamma,
                                              const float* beta,
                                              unsigned short* h) {
    __shared__ float scshS[2 * IN_C];
    gemm_phase<K, J, APPLY, XBF16>(xin, Wt, stats, gamma, beta, h,
                                   blockIdx.x, gridDim.x, scshS);
}

template <int D, bool LSM>
__global__ void agg_k(const unsigned short* h, const int* cnt, const int2* pairs,
                      unsigned short* outb, float* outf, const float* b3) {
    agg_phase<D, LSM>(h, cnt, pairs, outb, outf, b3);
}

__global__ void bn_stats_k(const unsigned short* a, float* sums) {
    __shared__ __align__(16) float smemF[2 * 10 * HID_C];
    bn_stats_phase(a, sums, smemF);
}

extern "C" void kernel_launch(void* const* d_in, const int* in_sizes, int n_in,
                              void* d_out, int out_size, void* d_ws, size_t ws_size,
                              hipStream_t stream) {
    GArgs a;
    a.x   = (const float*)d_in[0];
    a.ew  = (const float*)d_in[1];
    a.row = (const int*)d_in[2];
    a.col = (const int*)d_in[3];
    a.W1  = (const float*)d_in[4];
    // b1 = d_in[5], b2 = d_in[7]: cancel inside BatchNorm (mean absorbs them).
    a.W2  = (const float*)d_in[6];
    a.W3  = (const float*)d_in[8];
    a.b3  = (const float*)d_in[9];
    a.g1  = (const float*)d_in[10];
    a.be1 = (const float*)d_in[11];
    a.g2  = (const float*)d_in[12];
    a.be2 = (const float*)d_in[13];
    a.out = (float*)d_out;

    // Workspace: Bt bf16[N*96] | A bf16[N*96] | Wt1|Wt2|Wt3 bf16 |
    //            pairs int2[N*64] | cnt[N] | stats1[192] | stats2[192]
    a.Bt     = (unsigned short*)d_ws;
    a.A      = a.Bt + (size_t)N_NODES * HID_C;
    a.Wt1    = a.A + (size_t)N_NODES * HID_C;
    a.Wt2    = a.Wt1 + IN_C * HID_C;
    a.Wt3    = a.Wt2 + HID_C * HID_C;
    a.pairs  = (int2*)(a.Wt3 + HID_C * OUT_C);
    a.cnt    = (int*)(a.pairs + ((size_t)N_NODES << ELL_SHIFT));
    a.stats1 = (float*)(a.cnt + N_NODES);
    a.stats2 = a.stats1 + 2 * HID_C;

    void* kargs[] = { (void*)&a };
    hipError_t err = hipLaunchCooperativeKernel(
        (const void*)gcn_mega, dim3(GRID_BLKS), dim3(BLK), kargs, 0, stream);

    if (err != hipSuccess) {
        // Fallback: the proven R13 10-dispatch path.
        const int T = 256;
        const int gridE   = (N_EDGES + T - 1) / T;
        const int gridA96 = (N_NODES * (HID_C / 4) + T - 1) / T;
        const int gridA64 = (N_NODES * (OUT_C / 4) + T - 1) / T;
        const int gridG   = (N_NODES + 63) / 64;
        const int gridP   = (N_NODES + T - 1) / T;

        prep_all<<<gridP, T, 0, stream>>>(a.W1, a.W2, a.W3, a.Wt1, a.Wt2, a.Wt3,
                                          a.cnt, a.stats1);
        fill_ell<<<gridE, T, 0, stream>>>(a.row, a.col, a.ew, a.cnt, a.pairs);

        gemm_k<IN_C, HID_C, false, false><<<gridG, T, 0, stream>>>(
            a.x, a.Wt1, nullptr, nullptr, nullptr, a.A);
        agg_k<HID_C, false><<<gridA96, T, 0, stream>>>(
            a.A, a.cnt, a.pairs, a.Bt, nullptr, nullptr);
        bn_stats_k<<<250, T, 0, stream>>>(a.Bt, a.stats1);

        gemm_k<HID_C, HID_C, true, true><<<gridG, T, 0, stream>>>(
            a.Bt, a.Wt2, a.stats1, a.g1, a.be1, a.A);
        agg_k<HID_C, false><<<gridA96, T, 0, stream>>>(
            a.A, a.cnt, a.pairs, a.Bt, nullptr, nullptr);
        bn_stats_k<<<250, T, 0, stream>>>(a.Bt, a.stats2);

        gemm_k<HID_C, OUT_C, true, true><<<gridG, T, 0, stream>>>(
            a.Bt, a.Wt3, a.stats2, a.g2, a.be2, a.A);
        agg_k<OUT_C, true><<<gridA64, T, 0, stream>>>(
            a.A, a.cnt, a.pairs, nullptr, a.out, a.b3);
    }
}